// Round 13
// baseline (1481.298 us; speedup 1.0000x reference)
//
#include <hip/hip_runtime.h>

#define N_NODES 100000
#define E_EDGES 1600000
#define DIN 256
#define NH 4
#define DH 32
#define COUT 256
#define LN_EPS 1e-9f
#define BM 64
#define BK 32
#define KPAD (BK + 8)
#define NBUCK 1563            // ceil(N / 64)
#define BCAP  1280            // bucket capacity (mean 1024, +8 sigma)

typedef __attribute__((ext_vector_type(4))) float     f32x4;
typedef __attribute__((ext_vector_type(8))) _Float16  f16x8;

__device__ __forceinline__ ushort f2bf(float x) {
    union { float f; uint u; } v; v.f = x;
    uint r = v.u + 0x7fffu + ((v.u >> 16) & 1u);
    return (ushort)(r >> 16);
}

// ---------------------------------------------------------------------------
// W (2,4,256,32) f32 -> Wn[c][k] fp16 (N x K, row-major), c = o*128+h*32+q
// ---------------------------------------------------------------------------
__global__ __launch_bounds__(256) void wn_kernel(const float* __restrict__ W,
                                                 _Float16* __restrict__ Wn) {
    int i = blockIdx.x * 256 + threadIdx.x;   // 65536
    int c = i >> 8, k = i & 255;
    int o = c >> 7, h = (c >> 5) & 3, q = c & 31;
    Wn[i] = (_Float16)W[((o * NH + h) * DIN + k) * DH + q];
}

// ---------------------------------------------------------------------------
// FP16 MFMA GEMM: block = 64 rows x 256 cols, K=256 in 8 steps of 32.
// Fused epilogue: ReLU + per-head LN / att logits; feat_nei stored bf16.
// ---------------------------------------------------------------------------
__global__ __launch_bounds__(256) void gemm_kernel(
    const float* __restrict__ feat_in, const _Float16* __restrict__ Wn,
    const float* __restrict__ b, const float* __restrict__ att,
    const float* __restrict__ scale, const float* __restrict__ offset,
    float* __restrict__ out, ushort* __restrict__ feat_nei,
    float* __restrict__ att_s, float* __restrict__ att_n)
{
    __shared__ _Float16 sA[BM][KPAD];    // 5 KB
    __shared__ _Float16 sB[256][KPAD];   // 20 KB

    const int t   = threadIdx.x;
    const int wid = t >> 6;
    const int l   = t & 63;
    const int l15 = l & 15;
    const int lhi = l >> 4;
    const int m_blk = blockIdx.x * BM;

    f32x4 acc[4][4] = {};

    const int arow = t >> 2;
    const int akq  = t & 3;
    const int arow_g = min(m_blk + arow, N_NODES - 1);
    const float* aptr = feat_in + (size_t)arow_g * DIN + akq * 8;

    for (int kc = 0; kc < DIN; kc += BK) {
        float4 f0 = *(const float4*)(aptr + kc);
        float4 f1 = *(const float4*)(aptr + kc + 4);
        f16x8 ph = { (_Float16)f0.x, (_Float16)f0.y, (_Float16)f0.z,
                     (_Float16)f0.w, (_Float16)f1.x, (_Float16)f1.y,
                     (_Float16)f1.z, (_Float16)f1.w };
        *(f16x8*)&sA[arow][akq * 8] = ph;

#pragma unroll
        for (int i = 0; i < 4; ++i) {
            int c = i * 256 + t;
            int rrow = c >> 2, koff = (c & 3) * 8;
            *(f16x8*)&sB[rrow][koff] =
                *(const f16x8*)(Wn + rrow * 256 + kc + koff);
        }
        __syncthreads();

        f16x8 a[4], bb[4];
#pragma unroll
        for (int mi = 0; mi < 4; ++mi)
            a[mi] = *(f16x8*)&sA[mi * 16 + l15][lhi * 8];
#pragma unroll
        for (int ni = 0; ni < 4; ++ni)
            bb[ni] = *(f16x8*)&sB[wid * 64 + ni * 16 + l15][lhi * 8];
#pragma unroll
        for (int mi = 0; mi < 4; ++mi)
#pragma unroll
            for (int ni = 0; ni < 4; ++ni)
                acc[mi][ni] = __builtin_amdgcn_mfma_f32_16x16x32_f16(
                    a[mi], bb[ni], acc[mi][ni], 0, 0, 0);
        __syncthreads();
    }

    // ---- epilogue ----
    const int o = wid >> 1;
    float bias[4], attw[4], sc[4], of[4];
#pragma unroll
    for (int ni = 0; ni < 4; ++ni) {
        int c = wid * 64 + ni * 16 + l15;
        int h = (c >> 5) & 3;
        bias[ni] = b[c];
        sc[ni]   = scale[c];
        of[ni]   = offset[c];
        attw[ni] = att[h * 64 + o * 32 + (c & 31)];
    }

#pragma unroll
    for (int mi = 0; mi < 4; ++mi) {
#pragma unroll
        for (int r = 0; r < 4; ++r) {
            int row = m_blk + mi * 16 + lhi * 4 + r;
            float v[4];
#pragma unroll
            for (int ni = 0; ni < 4; ++ni)
                v[ni] = fmaxf(acc[mi][ni][r] + bias[ni], 0.f);
#pragma unroll
            for (int p = 0; p < 2; ++p) {
                float x0 = v[2 * p], x1 = v[2 * p + 1];
                float s1 = x0 + x1;
                float s2 = x0 * x0 + x1 * x1;
                float sa = x0 * attw[2 * p] + x1 * attw[2 * p + 1];
#pragma unroll
                for (int off = 1; off < 16; off <<= 1) {
                    s1 += __shfl_xor(s1, off);
                    s2 += __shfl_xor(s2, off);
                    sa += __shfl_xor(sa, off);
                }
                float mean = s1 * (1.f / 32.f);
                float var  = s2 * (1.f / 32.f) - mean * mean;
                float rstd = rsqrtf(fmaxf(var, 0.f) + LN_EPS);
                float a_out = sa >= 0.f ? sa : 0.2f * sa;
                if (row < N_NODES) {
                    int hloc = (wid & 1) * 2 + p;
                    if (o == 0) {
#pragma unroll
                        for (int q = 0; q < 2; ++q) {
                            int ni = 2 * p + q;
                            int c = wid * 64 + ni * 16 + l15;
                            out[(size_t)row * COUT + c] =
                                (v[ni] - mean) * rstd * sc[ni] + of[ni];
                        }
                        if (l15 == 0) att_s[hloc * N_NODES + row] = a_out;
                    } else {
#pragma unroll
                        for (int q = 0; q < 2; ++q) {
                            int ni = 2 * p + q;
                            int c = wid * 64 + ni * 16 + l15 - 128;
                            feat_nei[(size_t)row * 128 + c] = f2bf(v[ni]);
                        }
                        if (l15 == 0) att_n[hloc * N_NODES + row] = a_out;
                    }
                }
            }
        }
    }
}

// ---------------------------------------------------------------------------
// Binned append: block handles 4096 edges (strided by 256). LDS histogram
// over 1563 buckets (64 rows each) -> one global tail reservation per
// (block,bucket) -> contiguous record runs at bucket tails.
// Record: .x = col | (row&63)<<17 ; .y = f32 bits of adj.
// ---------------------------------------------------------------------------
__global__ __launch_bounds__(256) void bin_kernel(
    const int* __restrict__ row, const int* __restrict__ col,
    const float* __restrict__ adj, int* __restrict__ tail,
    uint2* __restrict__ eca)
{
    __shared__ int scnt[NBUCK];   // 6.25 KB
    for (int i = threadIdx.x; i < NBUCK; i += 256) scnt[i] = 0;
    __syncthreads();

    const int base = blockIdx.x * 4096 + threadIdx.x;
    uint br[16];
#pragma unroll
    for (int j = 0; j < 16; ++j) {
        int e = base + j * 256;
        uint v = 0xffffffffu;
        if (e < E_EDGES) {
            int bkt = row[e] >> 6;
            int r = atomicAdd(&scnt[bkt], 1);
            v = ((uint)bkt << 16) | (uint)r;   // bkt<=1562, r<4096
        }
        br[j] = v;
    }
    __syncthreads();
    // reserve contiguous runs; scnt[i] becomes this block's base in bucket i
    for (int i = threadIdx.x; i < NBUCK; i += 256) {
        int c = scnt[i];
        scnt[i] = (c > 0) ? atomicAdd(&tail[i], c) : 0;
    }
    __syncthreads();
#pragma unroll
    for (int j = 0; j < 16; ++j) {
        uint v = br[j];
        if (v != 0xffffffffu) {
            int e   = base + j * 256;
            int bkt = (int)(v >> 16);
            int r   = (int)(v & 0xffffu);
            int rl  = row[e] & 63;
            int slot = bkt * BCAP + scnt[bkt] + r;
            eca[slot] = make_uint2((uint)col[e] | ((uint)rl << 17),
                                   (uint)__float_as_int(adj[e]));
        }
    }
}

// ---------------------------------------------------------------------------
// Bucket aggregation: one block per bucket (64 rows). 32KB LDS f32 acc.
// 4 waves stream the bucket's records (2-edge pipelined); lane l handles
// channels 2l,2l+1 (head = l>>4); LDS atomic accumulate; fused LN -> out.
// ---------------------------------------------------------------------------
__global__ __launch_bounds__(256) void agg_kernel(
    const int* __restrict__ tail, const uint2* __restrict__ eca,
    const float* __restrict__ att_s, const float* __restrict__ att_n,
    const ushort* __restrict__ feat_nei,
    const float* __restrict__ scale, const float* __restrict__ offset,
    float* __restrict__ out)
{
    __shared__ float acc[64 * 128];   // 32 KB
    const int t = threadIdx.x;
    for (int i = t; i < 8192; i += 256) acc[i] = 0.f;
    __syncthreads();

    const int bkt = blockIdx.x;
    const int cntb = min(tail[bkt], BCAP);
    const int w = t >> 6, l = t & 63;
    const int h = l >> 4, c2 = l * 2;
    const uint2* ep = eca + (size_t)bkt * BCAP;
    const float* as_h = att_s + h * N_NODES + (bkt << 6);
    const float* an_h = att_n + h * N_NODES;

    int i = w;
    for (; i + 4 < cntb; i += 8) {
        uint2 r0 = ep[i];
        uint2 r1 = ep[i + 4];
        int c0 = r0.x & 0x1ffff, rl0 = r0.x >> 17;
        int c1 = r1.x & 0x1ffff, rl1 = r1.x >> 17;
        uint f0 = *(const uint*)&feat_nei[(size_t)c0 * 128 + c2];
        uint f1 = *(const uint*)&feat_nei[(size_t)c1 * 128 + c2];
        float w0 = (as_h[rl0] + an_h[c0]) * __uint_as_float(r0.y);
        float w1 = (as_h[rl1] + an_h[c1]) * __uint_as_float(r1.y);
        union { uint u; float f; } lo0, hi0, lo1, hi1;
        lo0.u = f0 << 16; hi0.u = f0 & 0xffff0000u;
        lo1.u = f1 << 16; hi1.u = f1 & 0xffff0000u;
        atomicAdd(&acc[rl0 * 128 + c2],     w0 * lo0.f);
        atomicAdd(&acc[rl0 * 128 + c2 + 1], w0 * hi0.f);
        atomicAdd(&acc[rl1 * 128 + c2],     w1 * lo1.f);
        atomicAdd(&acc[rl1 * 128 + c2 + 1], w1 * hi1.f);
    }
    for (; i < cntb; i += 4) {
        uint2 r0 = ep[i];
        int c0 = r0.x & 0x1ffff, rl0 = r0.x >> 17;
        uint f0 = *(const uint*)&feat_nei[(size_t)c0 * 128 + c2];
        float w0 = (as_h[rl0] + an_h[c0]) * __uint_as_float(r0.y);
        union { uint u; float f; } lo0, hi0;
        lo0.u = f0 << 16; hi0.u = f0 & 0xffff0000u;
        atomicAdd(&acc[rl0 * 128 + c2],     w0 * lo0.f);
        atomicAdd(&acc[rl0 * 128 + c2 + 1], w0 * hi0.f);
    }
    __syncthreads();

    // LN: thread t -> row-local t>>2, head t&3
    const int rl = t >> 2, h2 = t & 3;
    const int rown = (bkt << 6) + rl;
    if (rown < N_NODES) {
        float x[32];
        float s1 = 0.f, s2 = 0.f;
#pragma unroll
        for (int k = 0; k < 32; ++k) {
            float v = acc[rl * 128 + h2 * 32 + k];
            x[k] = v; s1 += v; s2 += v * v;
        }
        float mean = s1 * (1.f / 32.f);
        float var  = s2 * (1.f / 32.f) - mean * mean;
        float rstd = rsqrtf(fmaxf(var, 0.f) + LN_EPS);
#pragma unroll
        for (int k = 0; k < 32; ++k) {
            int ci = 128 + h2 * 32 + k;
            out[(size_t)rown * COUT + ci] =
                (x[k] - mean) * rstd * scale[ci] + offset[ci];
        }
    }
}

// ---------------------------------------------------------------------------
extern "C" void kernel_launch(void* const* d_in, const int* in_sizes, int n_in,
                              void* d_out, int out_size, void* d_ws, size_t ws_size,
                              hipStream_t stream)
{
    const float* feat_in = (const float*)d_in[0];
    const int*   row     = (const int*)d_in[1];
    const int*   col     = (const int*)d_in[2];
    const float* adj     = (const float*)d_in[3];
    const float* W       = (const float*)d_in[4];
    const float* b       = (const float*)d_in[5];
    const float* att     = (const float*)d_in[6];
    const float* scale   = (const float*)d_in[7];
    const float* offset  = (const float*)d_in[8];
    float* out = (float*)d_out;

    float*     ws     = (float*)d_ws;
    _Float16*  Wn     = (_Float16*)ws;               // 65536 fp16 = 32768 f32
    float*     att_s  = ws + 32768;                  // 400000
    float*     att_n  = att_s + NH * N_NODES;        // 400000
    ushort*    feat_b = (ushort*)(att_n + NH * N_NODES);  // N*128 bf16 = 6.4M f32
    int*       tail   = (int*)(feat_b + (size_t)N_NODES * 128);  // 1564 (even)
    uint2*     eca    = (uint2*)(tail + 1564);       // NBUCK*BCAP uint2 = 16 MB

    hipMemsetAsync(tail, 0, NBUCK * sizeof(int), stream);
    wn_kernel<<<256, 256, 0, stream>>>(W, Wn);
    gemm_kernel<<<(N_NODES + BM - 1) / BM, 256, 0, stream>>>(
        feat_in, Wn, b, att, scale, offset, out, feat_b, att_s, att_n);
    bin_kernel<<<(E_EDGES + 4095) / 4096, 256, 0, stream>>>(row, col, adj,
                                                            tail, eca);
    agg_kernel<<<NBUCK, 256, 0, stream>>>(tail, eca, att_s, att_n, feat_b,
                                          scale, offset, out);
}